// Round 1
// baseline (447.952 us; speedup 1.0000x reference)
//
#include <hip/hip_runtime.h>
#include <math.h>

#define DD 1024
#define N_NEUR 4096
#define L_TAB 4
#define K_FUN 8
#define T_TOK 256
#define S_SAMP 1024
#define C_CHUNK 32
#define BT 8192

typedef __attribute__((ext_vector_type(8))) short short8;
typedef __attribute__((ext_vector_type(4))) float f32x4;

static __device__ __forceinline__ unsigned short f2bf(float f) {
    union { float f; unsigned int u; } x; x.f = f;
    unsigned int u = x.u;
    unsigned int r = (u + 0x7fffu + ((u >> 16) & 1u)) >> 16;
    return (unsigned short)r;
}

// ---------------- LayerNorm: fp32 out + bf16 out ----------------
__global__ __launch_bounds__(256) void ln_kernel(const float* __restrict__ x,
                                                 const float* __restrict__ gamma,
                                                 const float* __restrict__ beta,
                                                 float* __restrict__ xn,
                                                 unsigned short* __restrict__ xnb) {
    int row = blockIdx.x, tid = threadIdx.x;
    int lane = tid & 63, w = tid >> 6;
    float4 v = ((const float4*)(x + (size_t)row * DD))[tid];
    float s = v.x + v.y + v.z + v.w;
    __shared__ float red[4];
    __shared__ float smu, srstd;
    for (int off = 32; off; off >>= 1) s += __shfl_down(s, off);
    if (lane == 0) red[w] = s;
    __syncthreads();
    if (tid == 0) smu = (red[0] + red[1] + red[2] + red[3]) * (1.0f / DD);
    __syncthreads();
    float mu = smu;
    float d0 = v.x - mu, d1 = v.y - mu, d2 = v.z - mu, d3 = v.w - mu;
    float s2 = d0 * d0 + d1 * d1 + d2 * d2 + d3 * d3;
    for (int off = 32; off; off >>= 1) s2 += __shfl_down(s2, off);
    if (lane == 0) red[w] = s2;
    __syncthreads();
    if (tid == 0) {
        float var = (red[0] + red[1] + red[2] + red[3]) * (1.0f / DD);
        srstd = 1.0f / sqrtf(var + 1e-12f);
    }
    __syncthreads();
    float rstd = srstd;
    int c0 = tid * 4;
    float o0 = d0 * rstd * gamma[c0 + 0] + beta[c0 + 0];
    float o1 = d1 * rstd * gamma[c0 + 1] + beta[c0 + 1];
    float o2 = d2 * rstd * gamma[c0 + 2] + beta[c0 + 2];
    float o3 = d3 * rstd * gamma[c0 + 3] + beta[c0 + 3];
    float4 o; o.x = o0; o.y = o1; o.z = o2; o.w = o3;
    ((float4*)(xn + (size_t)row * DD))[tid] = o;
    unsigned int p0 = ((unsigned int)f2bf(o1) << 16) | f2bf(o0);
    unsigned int p1 = ((unsigned int)f2bf(o3) << 16) | f2bf(o2);
    uint2 pk; pk.x = p0; pk.y = p1;
    ((uint2*)(xnb + (size_t)row * DD))[tid] = pk;
}

// ---------------- fp32 -> bf16 conversion of both weight matrices ----------------
__global__ __launch_bounds__(256) void cvt_kernel(const float* __restrict__ lshw,
                                                  const float* __restrict__ wts,
                                                  unsigned short* __restrict__ lshb,
                                                  unsigned short* __restrict__ wb) {
    size_t g = (size_t)blockIdx.x * 256 + threadIdx.x;   // float4 group, 2*1048576 total
    const float4* src; unsigned short* dst;
    if (g < 1048576) { src = (const float4*)lshw; dst = lshb; }
    else { src = (const float4*)wts; dst = wb; g -= 1048576; }
    float4 v = src[g];
    uint2 pk;
    pk.x = ((unsigned int)f2bf(v.y) << 16) | f2bf(v.x);
    pk.y = ((unsigned int)f2bf(v.w) << 16) | f2bf(v.z);
    ((uint2*)dst)[g] = pk;
}

// ---------------- SimHash codes (4 rows / block, fp32) ----------------
__global__ __launch_bounds__(256) void hash_kernel(const float* __restrict__ rows,
                                                   const float* __restrict__ hw,
                                                   int* __restrict__ codes) {
    int r0 = blockIdx.x * 4, tid = threadIdx.x;
    __shared__ float rb[4][1024];
    for (int i = 0; i < 4; ++i)
        *(float4*)&rb[i][tid * 4] = *(const float4*)(rows + (size_t)(r0 + i) * DD + tid * 4);
    __syncthreads();
    int p = tid >> 3, sub = tid & 7;          // p in [0,32): l = p>>3, k = p&7
    const float* h = hw + p * 1024;
    float acc0 = 0.f, acc1 = 0.f, acc2 = 0.f, acc3 = 0.f;
    for (int it = 0; it < 32; ++it) {
        int j = it * 32 + sub * 4;
        float4 hv = *(const float4*)(h + j);
        float4 x0 = *(const float4*)&rb[0][j];
        float4 x1 = *(const float4*)&rb[1][j];
        float4 x2 = *(const float4*)&rb[2][j];
        float4 x3 = *(const float4*)&rb[3][j];
        acc0 += hv.x * x0.x + hv.y * x0.y + hv.z * x0.z + hv.w * x0.w;
        acc1 += hv.x * x1.x + hv.y * x1.y + hv.z * x1.z + hv.w * x1.w;
        acc2 += hv.x * x2.x + hv.y * x2.y + hv.z * x2.z + hv.w * x2.w;
        acc3 += hv.x * x3.x + hv.y * x3.y + hv.z * x3.z + hv.w * x3.w;
    }
    for (int m = 4; m; m >>= 1) {
        acc0 += __shfl_xor(acc0, m); acc1 += __shfl_xor(acc1, m);
        acc2 += __shfl_xor(acc2, m); acc3 += __shfl_xor(acc3, m);
    }
    __shared__ int bitsm[4][32];
    if (sub == 0) {
        bitsm[0][p] = acc0 > 0.f; bitsm[1][p] = acc1 > 0.f;
        bitsm[2][p] = acc2 > 0.f; bitsm[3][p] = acc3 > 0.f;
    }
    __syncthreads();
    if (tid < 16) {
        int tk = tid >> 2, l = tid & 3;
        int code = 0;
        for (int k = 0; k < 8; ++k) code += bitsm[tk][l * 8 + k] << k;
        codes[(size_t)(r0 + tk) * 4 + l] = code;
    }
}

// ---------------- collision scores via per-table histograms ----------------
__global__ __launch_bounds__(256) void scores_kernel(const int* __restrict__ tcode,
                                                     const int* __restrict__ ncode,
                                                     int* __restrict__ scores) {
    int c = blockIdx.x, tid = threadIdx.x;
    __shared__ int hist[4][256];
    hist[0][tid] = 0; hist[1][tid] = 0; hist[2][tid] = 0; hist[3][tid] = 0;
    __syncthreads();
    const int* tc = tcode + (size_t)(c * T_TOK + tid) * 4;
    atomicAdd(&hist[0][tc[0]], 1); atomicAdd(&hist[1][tc[1]], 1);
    atomicAdd(&hist[2][tc[2]], 1); atomicAdd(&hist[3][tc[3]], 1);
    __syncthreads();
    for (int n = tid; n < N_NEUR; n += 256) {
        const int* nc = ncode + (size_t)n * 4;
        scores[(size_t)c * N_NEUR + n] =
            hist[0][nc[0]] + hist[1][nc[1]] + hist[2][nc[2]] + hist[3][nc[3]];
    }
}

// ---------------- top-S selection with jax.lax.top_k tie semantics ----------------
__global__ __launch_bounds__(256) void select_kernel(const int* __restrict__ scores,
                                                     int* __restrict__ ids) {
    int c = blockIdx.x, tid = threadIdx.x;
    __shared__ int hist[1025];
    __shared__ int sh[256];
    __shared__ int ctl[4];  // vstar, quota, eqBase, posBase
    for (int i = tid; i < 1025; i += 256) hist[i] = 0;
    __syncthreads();
    for (int n = tid; n < N_NEUR; n += 256) atomicAdd(&hist[scores[c * N_NEUR + n]], 1);
    __syncthreads();
    if (tid == 0) {
        int acc = 0, v = 1024;
        for (; v >= 0; --v) { acc += hist[v]; if (acc >= S_SAMP) break; }
        ctl[0] = v;
        ctl[1] = S_SAMP - (acc - hist[v]);  // quota among score==vstar
        ctl[2] = 0; ctl[3] = 0;
    }
    __syncthreads();
    int vstar = ctl[0];
    for (int pass = 0; pass < 16; ++pass) {
        int n = pass * 256 + tid;
        int sc = scores[c * N_NEUR + n];
        int gt = sc > vstar, eq = sc == vstar;
        sh[tid] = eq; __syncthreads();
        for (int off = 1; off < 256; off <<= 1) {
            int t = (tid >= off) ? sh[tid - off] : 0;
            __syncthreads(); sh[tid] += t; __syncthreads();
        }
        int eqIncl = sh[tid], eqTot = sh[255];
        __syncthreads();
        int inc = gt || (eq && (ctl[2] + eqIncl - eq) < ctl[1]);
        sh[tid] = inc; __syncthreads();
        for (int off = 1; off < 256; off <<= 1) {
            int t = (tid >= off) ? sh[tid - off] : 0;
            __syncthreads(); sh[tid] += t; __syncthreads();
        }
        int incIncl = sh[tid], incTot = sh[255];
        if (inc) ids[c * S_SAMP + ctl[3] + incIncl - 1] = n;
        __syncthreads();
        if (tid == 0) { ctl[2] += eqTot; ctl[3] += incTot; }
        __syncthreads();
    }
}

// ---------------- per-chunk token mean ----------------
__global__ __launch_bounds__(256) void xbar_kernel(const float* __restrict__ xn,
                                                   float* __restrict__ xbar) {
    int c = blockIdx.y, d = blockIdx.x * 256 + threadIdx.x;
    const float* base = xn + (size_t)c * T_TOK * DD + d;
    float s = 0.f;
    for (int t = 0; t < T_TOK; ++t) s += base[(size_t)t * DD];
    xbar[c * DD + d] = s * (1.0f / T_TOK);
}

// ---------------- gathered row-sums (pos + neg sets), fp32 ----------------
__global__ __launch_bounds__(256) void gathersum_kernel(const int* __restrict__ ids,
                                                        const float* __restrict__ lshw,
                                                        float* __restrict__ wps,
                                                        float* __restrict__ wns) {
    int c = blockIdx.y, d = blockIdx.x * 256 + threadIdx.x, tid = threadIdx.x;
    __shared__ int idl[S_SAMP];
    for (int i = tid; i < S_SAMP; i += 256) idl[i] = ids[c * S_SAMP + i];
    __syncthreads();
    float p = 0.f, n = 0.f;
    for (int s = 0; s < S_SAMP; ++s) {
        int r = idl[s];
        p += lshw[(size_t)r * DD + d];
        n += lshw[(size_t)((r + 2048) & 4095) * DD + d];
    }
    wps[c * DD + d] = p; wns[c * DD + d] = n;
}

// ---------------- per-chunk triplet loss ----------------
__global__ __launch_bounds__(256) void triplet_kernel(const float* __restrict__ xbar,
                                                      const float* __restrict__ wps,
                                                      const float* __restrict__ wns,
                                                      float* __restrict__ closs) {
    int c = blockIdx.x, tid = threadIdx.x;
    int lane = tid & 63, w = tid >> 6;
    float p = 0.f, n = 0.f;
    for (int d = tid; d < DD; d += 256) {
        float xb = xbar[c * DD + d];
        p += xb * wps[c * DD + d];
        n += xb * wns[c * DD + d];
    }
    for (int off = 32; off; off >>= 1) { p += __shfl_down(p, off); n += __shfl_down(n, off); }
    __shared__ float rp[4], rn[4];
    if (lane == 0) { rp[w] = p; rn[w] = n; }
    __syncthreads();
    if (tid == 0) {
        float pm = (rp[0] + rp[1] + rp[2] + rp[3]) * (1.0f / S_SAMP);
        float nm = (rn[0] + rn[1] + rn[2] + rn[3]) * (1.0f / S_SAMP);
        float l = 0.1f + nm - pm;
        closs[c] = l > 0.f ? l : 0.f;
    }
}

__global__ void final_loss_kernel(const float* __restrict__ closs, float* __restrict__ out) {
    int tid = threadIdx.x;
    float v = (tid < C_CHUNK) ? closs[tid] : 0.f;
    for (int off = 32; off; off >>= 1) v += __shfl_down(v, off);
    if (tid == 0) out[8388608] = v * (1.0f / C_CHUNK);
}

// ---------------- GEMM A: logits = xn * lsh[ids]^T -> gelu -> act (bf16) ----------------
__global__ __launch_bounds__(256) void gemmA_kernel(const unsigned short* __restrict__ xnb,
                                                    const unsigned short* __restrict__ lshb,
                                                    const int* __restrict__ ids,
                                                    unsigned short* __restrict__ act) {
    int nt = blockIdx.x, mt = blockIdx.y, c = blockIdx.z;
    int tid = threadIdx.x;
    __shared__ unsigned short la[64][40];
    __shared__ unsigned short lb[64][40];
    __shared__ int idl[64];
    if (tid < 64) idl[tid] = ids[c * S_SAMP + nt * 64 + tid];
    __syncthreads();
    int row = tid >> 2, seg = tid & 3;
    const unsigned short* arow = xnb + (size_t)(c * T_TOK + mt * 64 + row) * DD + seg * 8;
    int lane = tid & 63, w = tid >> 6, lr = lane & 15, kh = lane >> 4;
    f32x4 acc[4];
    for (int nf = 0; nf < 4; ++nf) acc[nf] = (f32x4){0.f, 0.f, 0.f, 0.f};
    const unsigned short* brow = lshb + (size_t)idl[row] * DD + seg * 8;
    for (int kk = 0; kk < 32; ++kk) {
        int k0 = kk * 32;
        short8 va = *(const short8*)(arow + k0);
        short8 vb = *(const short8*)(brow + k0);
        *(short8*)&la[row][seg * 8] = va;
        *(short8*)&lb[row][seg * 8] = vb;
        __syncthreads();
        short8 af = *(const short8*)&la[w * 16 + lr][kh * 8];
#pragma unroll
        for (int nf = 0; nf < 4; ++nf) {
            short8 bf = *(const short8*)&lb[nf * 16 + lr][kh * 8];
            acc[nf] = __builtin_amdgcn_mfma_f32_16x16x32_bf16(af, bf, acc[nf], 0, 0, 0);
        }
        __syncthreads();
    }
#pragma unroll
    for (int nf = 0; nf < 4; ++nf) {
        int s = nt * 64 + nf * 16 + lr;
#pragma unroll
        for (int j = 0; j < 4; ++j) {
            int t = mt * 64 + w * 16 + kh * 4 + j;
            float v = acc[nf][j];
            float g = 0.5f * v * (1.0f + erff(v * 0.70710678118654752f));
            act[(size_t)(c * T_TOK + t) * DD + s] = f2bf(g);
        }
    }
}

// ---------------- GEMM B: out = act * weights[ids] + bias (fp32 out) ----------------
__global__ __launch_bounds__(256) void gemmB_kernel(const unsigned short* __restrict__ act,
                                                    const unsigned short* __restrict__ wb,
                                                    const int* __restrict__ ids,
                                                    const float* __restrict__ bias,
                                                    float* __restrict__ out) {
    int nt = blockIdx.x, mt = blockIdx.y, c = blockIdx.z;
    int tid = threadIdx.x;
    __shared__ unsigned short la[64][40];
    __shared__ unsigned short lbt[64][40];  // [d_local][s_local] transposed tile
    __shared__ int idl[S_SAMP];
    for (int i = tid; i < S_SAMP; i += 256) idl[i] = ids[c * S_SAMP + i];
    __syncthreads();
    int row = tid >> 2, seg = tid & 3;   // A staging
    int sl = tid >> 3, dseg = tid & 7;   // B staging (32 s-rows x 8 d-segs)
    const unsigned short* arow = act + (size_t)(c * T_TOK + mt * 64 + row) * DD + seg * 8;
    int lane = tid & 63, w = tid >> 6, lr = lane & 15, kh = lane >> 4;
    f32x4 acc[4];
    for (int nf = 0; nf < 4; ++nf) acc[nf] = (f32x4){0.f, 0.f, 0.f, 0.f};
    for (int kk = 0; kk < 32; ++kk) {
        int k0 = kk * 32;
        short8 va = *(const short8*)(arow + k0);
        int grow = idl[k0 + sl];
        short8 vb = *(const short8*)(wb + (size_t)grow * DD + nt * 64 + dseg * 8);
        *(short8*)&la[row][seg * 8] = va;
#pragma unroll
        for (int i = 0; i < 8; ++i) lbt[dseg * 8 + i][sl] = (unsigned short)vb[i];
        __syncthreads();
        short8 af = *(const short8*)&la[w * 16 + lr][kh * 8];
#pragma unroll
        for (int nf = 0; nf < 4; ++nf) {
            short8 bf = *(const short8*)&lbt[nf * 16 + lr][kh * 8];
            acc[nf] = __builtin_amdgcn_mfma_f32_16x16x32_bf16(af, bf, acc[nf], 0, 0, 0);
        }
        __syncthreads();
    }
#pragma unroll
    for (int nf = 0; nf < 4; ++nf) {
        int d = nt * 64 + nf * 16 + lr;
        float bs = bias[d];
#pragma unroll
        for (int j = 0; j < 4; ++j) {
            int t = mt * 64 + w * 16 + kh * 4 + j;
            out[(size_t)(c * T_TOK + t) * DD + d] = acc[nf][j] + bs;
        }
    }
}

extern "C" void kernel_launch(void* const* d_in, const int* in_sizes, int n_in,
                              void* d_out, int out_size, void* d_ws, size_t ws_size,
                              hipStream_t stream) {
    const float* hs   = (const float*)d_in[0];
    const float* g    = (const float*)d_in[1];
    const float* be   = (const float*)d_in[2];
    const float* lshw = (const float*)d_in[3];
    const float* wts  = (const float*)d_in[4];
    const float* bias = (const float*)d_in[5];
    const float* hw   = (const float*)d_in[6];
    float* out = (float*)d_out;

    char* ws = (char*)d_ws;
    float* xn             = (float*)ws;          ws += 33554432;  // 8192x1024 f32
    unsigned short* xnb   = (unsigned short*)ws; ws += 16777216;  // 8192x1024 bf16
    unsigned short* lshb  = (unsigned short*)ws; ws += 8388608;   // 4096x1024 bf16
    unsigned short* wb    = (unsigned short*)ws; ws += 8388608;   // 4096x1024 bf16
    unsigned short* actb  = (unsigned short*)ws; ws += 16777216;  // 32x256x1024 bf16
    int* tcode            = (int*)ws;            ws += 131072;    // 8192x4
    int* ncode            = (int*)ws;            ws += 65536;     // 4096x4
    int* scores           = (int*)ws;            ws += 524288;    // 32x4096
    int* ids              = (int*)ws;            ws += 131072;    // 32x1024
    float* xbar           = (float*)ws;          ws += 131072;    // 32x1024
    float* wps            = (float*)ws;          ws += 131072;    // 32x1024
    float* wns            = (float*)ws;          ws += 131072;    // 32x1024
    float* closs          = (float*)ws;          ws += 128;       // 32

    ln_kernel<<<8192, 256, 0, stream>>>(hs, g, be, xn, xnb);
    cvt_kernel<<<8192, 256, 0, stream>>>(lshw, wts, lshb, wb);
    hash_kernel<<<2048, 256, 0, stream>>>(xn, hw, tcode);
    hash_kernel<<<1024, 256, 0, stream>>>(lshw, hw, ncode);
    scores_kernel<<<32, 256, 0, stream>>>(tcode, ncode, scores);
    select_kernel<<<32, 256, 0, stream>>>(scores, ids);
    xbar_kernel<<<dim3(4, 32), 256, 0, stream>>>(xn, xbar);
    gathersum_kernel<<<dim3(4, 32), 256, 0, stream>>>(ids, lshw, wps, wns);
    triplet_kernel<<<32, 256, 0, stream>>>(xbar, wps, wns, closs);
    gemmA_kernel<<<dim3(16, 4, 32), 256, 0, stream>>>(xnb, lshb, ids, actb);
    gemmB_kernel<<<dim3(16, 4, 32), 256, 0, stream>>>(actb, wb, ids, bias, out);
    final_loss_kernel<<<1, 64, 0, stream>>>(closs, out);
}

// Round 5
// 258.595 us; speedup vs baseline: 1.7323x; 1.7323x over previous
//
#include <hip/hip_runtime.h>
#include <math.h>

#define DD 1024
#define N_NEUR 4096
#define T_TOK 256
#define S_SAMP 1024
#define C_CHUNK 32

typedef __attribute__((ext_vector_type(8))) short short8;
typedef __attribute__((ext_vector_type(4))) float f32x4;

#define AS1Q __attribute__((address_space(1)))
#define AS3Q __attribute__((address_space(3)))

static __device__ __forceinline__ void gld16(const void* g, void* s) {
    __builtin_amdgcn_global_load_lds((AS1Q void*)g, (AS3Q void*)s, 16, 0, 0);
}

static __device__ __forceinline__ unsigned short f2bf(float f) {
    union { float f; unsigned int u; } x; x.f = f;
    unsigned int u = x.u;
    unsigned int r = (u + 0x7fffu + ((u >> 16) & 1u)) >> 16;
    return (unsigned short)r;
}
static __device__ __forceinline__ float bf2f(unsigned short b) {
    return __uint_as_float(((unsigned int)b) << 16);
}

// ---------------- LayerNorm: fp32 out + bf16 out ----------------
__global__ __launch_bounds__(256) void ln_kernel(const float* __restrict__ x,
                                                 const float* __restrict__ gamma,
                                                 const float* __restrict__ beta,
                                                 float* __restrict__ xn,
                                                 unsigned short* __restrict__ xnb) {
    int row = blockIdx.x, tid = threadIdx.x;
    int lane = tid & 63, w = tid >> 6;
    float4 v = ((const float4*)(x + (size_t)row * DD))[tid];
    float s = v.x + v.y + v.z + v.w;
    __shared__ float red[4];
    __shared__ float smu, srstd;
    for (int off = 32; off; off >>= 1) s += __shfl_down(s, off);
    if (lane == 0) red[w] = s;
    __syncthreads();
    if (tid == 0) smu = (red[0] + red[1] + red[2] + red[3]) * (1.0f / DD);
    __syncthreads();
    float mu = smu;
    float d0 = v.x - mu, d1 = v.y - mu, d2 = v.z - mu, d3 = v.w - mu;
    float s2 = d0 * d0 + d1 * d1 + d2 * d2 + d3 * d3;
    for (int off = 32; off; off >>= 1) s2 += __shfl_down(s2, off);
    if (lane == 0) red[w] = s2;
    __syncthreads();
    if (tid == 0) {
        float var = (red[0] + red[1] + red[2] + red[3]) * (1.0f / DD);
        srstd = 1.0f / sqrtf(var + 1e-12f);
    }
    __syncthreads();
    float rstd = srstd;
    int c0 = tid * 4;
    float o0 = d0 * rstd * gamma[c0 + 0] + beta[c0 + 0];
    float o1 = d1 * rstd * gamma[c0 + 1] + beta[c0 + 1];
    float o2 = d2 * rstd * gamma[c0 + 2] + beta[c0 + 2];
    float o3 = d3 * rstd * gamma[c0 + 3] + beta[c0 + 3];
    float4 o; o.x = o0; o.y = o1; o.z = o2; o.w = o3;
    ((float4*)(xn + (size_t)row * DD))[tid] = o;
    uint2 pk;
    pk.x = ((unsigned int)f2bf(o1) << 16) | f2bf(o0);
    pk.y = ((unsigned int)f2bf(o3) << 16) | f2bf(o2);
    ((uint2*)(xnb + (size_t)row * DD))[tid] = pk;
}

// ---------------- fp32 -> bf16 conversion of both weight matrices ----------------
__global__ __launch_bounds__(256) void cvt_kernel(const float* __restrict__ lshw,
                                                  const float* __restrict__ wts,
                                                  unsigned short* __restrict__ lshb,
                                                  unsigned short* __restrict__ wb) {
    size_t g = (size_t)blockIdx.x * 256 + threadIdx.x;
    const float4* src; unsigned short* dst;
    if (g < 1048576) { src = (const float4*)lshw; dst = lshb; }
    else { src = (const float4*)wts; dst = wb; g -= 1048576; }
    float4 v = src[g];
    uint2 pk;
    pk.x = ((unsigned int)f2bf(v.y) << 16) | f2bf(v.x);
    pk.y = ((unsigned int)f2bf(v.w) << 16) | f2bf(v.z);
    ((uint2*)dst)[g] = pk;
}

// ---------------- SimHash codes (4 rows / block, fp32), tokens + neurons ----------------
__global__ __launch_bounds__(256) void hash_kernel(const float* __restrict__ xn,
                                                   const float* __restrict__ lshw,
                                                   const float* __restrict__ hw,
                                                   int* __restrict__ tcode,
                                                   int* __restrict__ ncode) {
    int b = blockIdx.x, tid = threadIdx.x;
    const float* rows; int* codes; int r0;
    if (b < 2048) { rows = xn; codes = tcode; r0 = b * 4; }
    else { rows = lshw; codes = ncode; r0 = (b - 2048) * 4; }
    __shared__ float rb[4][1024];
    for (int i = 0; i < 4; ++i)
        *(float4*)&rb[i][tid * 4] = *(const float4*)(rows + (size_t)(r0 + i) * DD + tid * 4);
    __syncthreads();
    int p = tid >> 3, sub = tid & 7;
    const float* h = hw + p * 1024;
    float acc0 = 0.f, acc1 = 0.f, acc2 = 0.f, acc3 = 0.f;
    for (int it = 0; it < 32; ++it) {
        int j = it * 32 + sub * 4;
        float4 hv = *(const float4*)(h + j);
        float4 x0 = *(const float4*)&rb[0][j];
        float4 x1 = *(const float4*)&rb[1][j];
        float4 x2 = *(const float4*)&rb[2][j];
        float4 x3 = *(const float4*)&rb[3][j];
        acc0 += hv.x * x0.x + hv.y * x0.y + hv.z * x0.z + hv.w * x0.w;
        acc1 += hv.x * x1.x + hv.y * x1.y + hv.z * x1.z + hv.w * x1.w;
        acc2 += hv.x * x2.x + hv.y * x2.y + hv.z * x2.z + hv.w * x2.w;
        acc3 += hv.x * x3.x + hv.y * x3.y + hv.z * x3.z + hv.w * x3.w;
    }
    for (int m = 4; m; m >>= 1) {
        acc0 += __shfl_xor(acc0, m); acc1 += __shfl_xor(acc1, m);
        acc2 += __shfl_xor(acc2, m); acc3 += __shfl_xor(acc3, m);
    }
    __shared__ int bitsm[4][32];
    if (sub == 0) {
        bitsm[0][p] = acc0 > 0.f; bitsm[1][p] = acc1 > 0.f;
        bitsm[2][p] = acc2 > 0.f; bitsm[3][p] = acc3 > 0.f;
    }
    __syncthreads();
    if (tid < 16) {
        int tk = tid >> 2, l = tid & 3;
        int code = 0;
        for (int k = 0; k < 8; ++k) code += bitsm[tk][l * 8 + k] << k;
        codes[(size_t)(r0 + tk) * 4 + l] = code;
    }
}

// ---------------- scores + top-S selection fused ----------------
__global__ __launch_bounds__(256) void scoresel_kernel(const int* __restrict__ tcode,
                                                       const int* __restrict__ ncode,
                                                       int* __restrict__ ids) {
    int c = blockIdx.x, tid = threadIdx.x;
    __shared__ int hist4[4][256];
    __shared__ short sc[4096];
    __shared__ int hist[1025];
    __shared__ int gs[64];
    __shared__ int ctl[4];
    __shared__ int wsum[4];
    hist4[0][tid] = 0; hist4[1][tid] = 0; hist4[2][tid] = 0; hist4[3][tid] = 0;
    for (int i = tid; i < 1025; i += 256) hist[i] = 0;
    __syncthreads();
    const int* tc = tcode + (size_t)(c * T_TOK + tid) * 4;
    atomicAdd(&hist4[0][tc[0]], 1); atomicAdd(&hist4[1][tc[1]], 1);
    atomicAdd(&hist4[2][tc[2]], 1); atomicAdd(&hist4[3][tc[3]], 1);
    __syncthreads();
    for (int n = tid; n < N_NEUR; n += 256) {
        const int* nc = ncode + (size_t)n * 4;
        int s = hist4[0][nc[0]] + hist4[1][nc[1]] + hist4[2][nc[2]] + hist4[3][nc[3]];
        sc[n] = (short)s;
        atomicAdd(&hist[s], 1);
    }
    __syncthreads();
    if (tid < 64) {
        int g = 0;
        for (int i = 0; i < 16; ++i) g += hist[tid * 16 + i];
        gs[tid] = g;
    }
    __syncthreads();
    if (tid == 0) {
        int acc = hist[1024], v = 1024;
        if (acc < S_SAMP) {
            int gi;
            for (gi = 63; gi >= 0; --gi) {
                if (acc + gs[gi] >= S_SAMP) break;
                acc += gs[gi];
            }
            for (v = gi * 16 + 15; v >= 0; --v) { acc += hist[v]; if (acc >= S_SAMP) break; }
        }
        ctl[0] = v;
        ctl[1] = S_SAMP - (acc - hist[v]);  // quota among score==vstar
        ctl[2] = 0; ctl[3] = 0;
    }
    __syncthreads();
    int vstar = ctl[0], quota = ctl[1];
    int lane = tid & 63, w = tid >> 6;
    for (int pass = 0; pass < 16; ++pass) {
        int n = pass * 256 + tid;
        int s = sc[n];
        int gt = s > vstar, eq = s == vstar;
        unsigned long long m = __ballot(eq != 0);
        int wr = __popcll(m & ((1ull << lane) - 1ull));
        if (lane == 0) wsum[w] = __popcll(m);
        __syncthreads();
        int base = ctl[2];
        if (w > 0) base += wsum[0];
        if (w > 1) base += wsum[1];
        if (w > 2) base += wsum[2];
        int eqr = base + wr;
        if (gt || (eq && eqr < quota)) {
            int p = atomicAdd(&ctl[3], 1);
            ids[c * S_SAMP + p] = n;
        }
        __syncthreads();
        if (tid == 0) ctl[2] += wsum[0] + wsum[1] + wsum[2] + wsum[3];
        __syncthreads();
    }
}

// ---------------- per-chunk token mean (bf16 in) ----------------
__global__ __launch_bounds__(256) void xbar_kernel(const unsigned short* __restrict__ xnb,
                                                   float* __restrict__ xbar) {
    int c = blockIdx.y, d = blockIdx.x * 256 + threadIdx.x;
    const unsigned short* base = xnb + (size_t)c * T_TOK * DD + d;
    float s = 0.f;
    for (int t = 0; t < T_TOK; ++t) s += bf2f(base[(size_t)t * DD]);
    xbar[c * DD + d] = s * (1.0f / T_TOK);
}

// ---------------- gathered row-sum partials (pos + neg), bf16 in ----------------
__global__ __launch_bounds__(256) void gathersum_kernel(const int* __restrict__ ids,
                                                        const unsigned short* __restrict__ lshb,
                                                        float* __restrict__ wpsp,
                                                        float* __restrict__ wnsp) {
    int sseg = blockIdx.x, c = blockIdx.y, tid = threadIdx.x;
    __shared__ int idl[64];
    if (tid < 64) idl[tid] = ids[c * S_SAMP + sseg * 64 + tid];
    __syncthreads();
    float4 ap = {0.f, 0.f, 0.f, 0.f}, an = {0.f, 0.f, 0.f, 0.f};
    for (int s = 0; s < 64; ++s) {
        int r = idl[s], rn = r ^ 2048;
        uint2 up = ((const uint2*)(lshb + (size_t)r * DD))[tid];
        uint2 un = ((const uint2*)(lshb + (size_t)rn * DD))[tid];
        ap.x += __uint_as_float(up.x << 16);  ap.y += __uint_as_float(up.x & 0xffff0000u);
        ap.z += __uint_as_float(up.y << 16);  ap.w += __uint_as_float(up.y & 0xffff0000u);
        an.x += __uint_as_float(un.x << 16);  an.y += __uint_as_float(un.x & 0xffff0000u);
        an.z += __uint_as_float(un.y << 16);  an.w += __uint_as_float(un.y & 0xffff0000u);
    }
    size_t base = (size_t)(sseg * 32 + c) * DD + tid * 4;
    *(float4*)(wpsp + base) = ap;
    *(float4*)(wnsp + base) = an;
}

// ---------------- per-chunk triplet loss (reduces the 16 partials) ----------------
__global__ __launch_bounds__(256) void triplet_kernel(const float* __restrict__ xbar,
                                                      const float* __restrict__ wpsp,
                                                      const float* __restrict__ wnsp,
                                                      float* __restrict__ closs) {
    int c = blockIdx.x, tid = threadIdx.x;
    int lane = tid & 63, w = tid >> 6;
    float xb0 = xbar[c * DD + tid],       xb1 = xbar[c * DD + tid + 256];
    float xb2 = xbar[c * DD + tid + 512], xb3 = xbar[c * DD + tid + 768];
    float p = 0.f, n = 0.f;
    for (int seg = 0; seg < 16; ++seg) {
        const float* wp = wpsp + (size_t)(seg * 32 + c) * DD;
        const float* wn = wnsp + (size_t)(seg * 32 + c) * DD;
        p += xb0 * wp[tid] + xb1 * wp[tid + 256] + xb2 * wp[tid + 512] + xb3 * wp[tid + 768];
        n += xb0 * wn[tid] + xb1 * wn[tid + 256] + xb2 * wn[tid + 512] + xb3 * wn[tid + 768];
    }
    for (int off = 32; off; off >>= 1) { p += __shfl_down(p, off); n += __shfl_down(n, off); }
    __shared__ float rp[4], rn_[4];
    if (lane == 0) { rp[w] = p; rn_[w] = n; }
    __syncthreads();
    if (tid == 0) {
        float pm = (rp[0] + rp[1] + rp[2] + rp[3]) * (1.0f / S_SAMP);
        float nm = (rn_[0] + rn_[1] + rn_[2] + rn_[3]) * (1.0f / S_SAMP);
        float l = 0.1f + nm - pm;
        closs[c] = l > 0.f ? l : 0.f;
    }
}

__global__ void final_loss_kernel(const float* __restrict__ closs, float* __restrict__ out) {
    int tid = threadIdx.x;
    float v = (tid < C_CHUNK) ? closs[tid] : 0.f;
    for (int off = 32; off; off >>= 1) v += __shfl_down(v, off);
    if (tid == 0) out[8388608] = v * (1.0f / C_CHUNK);
}

// ---------------- GEMM A: logits = xn * lsh[ids]^T -> gelu -> act (bf16) ----------------
// 128x128 tile, BK=32, 4 waves (2x2), global_load_lds staging (m97 structure)
__global__ __launch_bounds__(256) void gemmA_kernel(const unsigned short* __restrict__ xnb,
                                                    const unsigned short* __restrict__ lshb,
                                                    const int* __restrict__ ids,
                                                    unsigned short* __restrict__ act) {
    int nt = blockIdx.x, mt = blockIdx.y, c = blockIdx.z;
    int tid = threadIdx.x;
    __shared__ __align__(16) unsigned short la[128 * 32];
    __shared__ __align__(16) unsigned short lb[128 * 32];
    __shared__ int idl[128];
    if (tid < 128) idl[tid] = ids[c * S_SAMP + nt * 128 + tid];
    __syncthreads();
    int l = tid & 63, w = tid >> 6;
    int wm = w >> 1, wn = w & 1;
    int lr = l & 15, kh = l >> 4;
    int r0 = w * 16 + (l >> 2), r1 = 64 + r0;
    int ksg = (l & 3) * 8;
    const unsigned short* a0 = xnb + (size_t)(c * T_TOK + mt * 128 + r0) * DD + ksg;
    const unsigned short* a1 = xnb + (size_t)(c * T_TOK + mt * 128 + r1) * DD + ksg;
    const unsigned short* b0 = lshb + (size_t)idl[r0] * DD + ksg;
    const unsigned short* b1 = lshb + (size_t)idl[r1] * DD + ksg;
    char* sA0 = (char*)la + w * 1024;
    char* sA1 = (char*)la + 4096 + w * 1024;
    char* sB0 = (char*)lb + w * 1024;
    char* sB1 = (char*)lb + 4096 + w * 1024;
    f32x4 acc[4][4];
#pragma unroll
    for (int mf = 0; mf < 4; ++mf)
#pragma unroll
        for (int nf = 0; nf < 4; ++nf) acc[mf][nf] = (f32x4){0.f, 0.f, 0.f, 0.f};
    for (int kk = 0; kk < 32; ++kk) {
        int ko = kk * 32;
        gld16(a0 + ko, sA0); gld16(a1 + ko, sA1);
        gld16(b0 + ko, sB0); gld16(b1 + ko, sB1);
        __syncthreads();
        short8 af[4];
#pragma unroll
        for (int mf = 0; mf < 4; ++mf)
            af[mf] = *(const short8*)&la[(wm * 64 + mf * 16 + lr) * 32 + kh * 8];
#pragma unroll
        for (int nf = 0; nf < 4; ++nf) {
            short8 bf = *(const short8*)&lb[(wn * 64 + nf * 16 + lr) * 32 + kh * 8];
#pragma unroll
            for (int mf = 0; mf < 4; ++mf)
                acc[mf][nf] = __builtin_amdgcn_mfma_f32_16x16x32_bf16(af[mf], bf, acc[mf][nf], 0, 0, 0);
        }
        __syncthreads();
    }
#pragma unroll
    for (int mf = 0; mf < 4; ++mf)
#pragma unroll
        for (int nf = 0; nf < 4; ++nf) {
            int sg = nt * 128 + wn * 64 + nf * 16 + lr;
#pragma unroll
            for (int j = 0; j < 4; ++j) {
                int tg = c * T_TOK + mt * 128 + wm * 64 + mf * 16 + kh * 4 + j;
                float v = acc[mf][nf][j];
                float gl = 0.5f * v * (1.0f + erff(v * 0.70710678118654752f));
                act[(size_t)tg * DD + sg] = f2bf(gl);
            }
        }
}

// ---------------- GEMM B: out = act * weights[ids] + bias (fp32 out) ----------------
// B tile staged LINEARLY as [32 s][128 d] via global_load_lds; B fragments built
// with 8x ds_read_u16 (base + immediate offsets). Unambiguous semantics.
__global__ __launch_bounds__(256) void gemmB_kernel(const unsigned short* __restrict__ act,
                                                    const unsigned short* __restrict__ wb,
                                                    const int* __restrict__ ids,
                                                    const float* __restrict__ bias,
                                                    float* __restrict__ out) {
    int nt = blockIdx.x, mt = blockIdx.y, c = blockIdx.z;
    int tid = threadIdx.x;
    __shared__ __align__(16) unsigned short la[128 * 32];
    __shared__ __align__(16) unsigned short lb[32 * 128];   // [s][d] linear
    __shared__ int idl[S_SAMP];
    for (int i = tid; i < S_SAMP; i += 256) idl[i] = ids[c * S_SAMP + i];
    __syncthreads();
    int l = tid & 63, w = tid >> 6;
    int wm = w >> 1, wn = w & 1;
    int lr = l & 15, kh = l >> 4;
    int r0 = w * 16 + (l >> 2), r1 = 64 + r0;
    int ksg = (l & 3) * 8;
    const unsigned short* a0 = act + (size_t)(c * T_TOK + mt * 128 + r0) * DD + ksg;
    const unsigned short* a1 = act + (size_t)(c * T_TOK + mt * 128 + r1) * DD + ksg;
    char* sA0 = (char*)la + w * 1024;
    char* sA1 = (char*)la + 4096 + w * 1024;
    char* sB0 = (char*)lb + w * 1024;
    char* sB1 = (char*)lb + 4096 + w * 1024;
    // B staging: dest elem w*512 + l*8 == (w*4 + (l>>4))*128 + (l&15)*8
    int srow0 = w * 4 + (l >> 4);   // k-row staged (0..15), sB1 does 16..31
    int srow1 = 16 + srow0;
    int dcol = nt * 128 + (l & 15) * 8;
    const unsigned short* lbn = &lb[wn * 64 + lr];  // + kh*1024 folded below
    f32x4 acc[4][4];
#pragma unroll
    for (int mf = 0; mf < 4; ++mf)
#pragma unroll
        for (int nf = 0; nf < 4; ++nf) acc[mf][nf] = (f32x4){0.f, 0.f, 0.f, 0.f};
    for (int kk = 0; kk < 32; ++kk) {
        int ko = kk * 32;
        int id0 = idl[ko + srow0], id1 = idl[ko + srow1];
        gld16(a0 + ko, sA0); gld16(a1 + ko, sA1);
        gld16(wb + (size_t)id0 * DD + dcol, sB0);
        gld16(wb + (size_t)id1 * DD + dcol, sB1);
        __syncthreads();
        short8 af[4];
#pragma unroll
        for (int mf = 0; mf < 4; ++mf)
            af[mf] = *(const short8*)&la[(wm * 64 + mf * 16 + lr) * 32 + kh * 8];
#pragma unroll
        for (int nf = 0; nf < 4; ++nf) {
            const unsigned short* bp = lbn + kh * 1024 + nf * 16;
            short8 bf;
#pragma unroll
            for (int j = 0; j < 8; ++j) bf[j] = (short)bp[j * 128];
#pragma unroll
            for (int mf = 0; mf < 4; ++mf)
                acc[mf][nf] = __builtin_amdgcn_mfma_f32_16x16x32_bf16(af[mf], bf, acc[mf][nf], 0, 0, 0);
        }
        __syncthreads();
    }
#pragma unroll
    for (int mf = 0; mf < 4; ++mf)
#pragma unroll
        for (int nf = 0; nf < 4; ++nf) {
            int d = nt * 128 + wn * 64 + nf * 16 + lr;
            float bs = bias[d];
#pragma unroll
            for (int j = 0; j < 4; ++j) {
                int tg = c * T_TOK + mt * 128 + wm * 64 + mf * 16 + kh * 4 + j;
                out[(size_t)tg * DD + d] = acc[mf][nf][j] + bs;
            }
        }
}

extern "C" void kernel_launch(void* const* d_in, const int* in_sizes, int n_in,
                              void* d_out, int out_size, void* d_ws, size_t ws_size,
                              hipStream_t stream) {
    const float* hs   = (const float*)d_in[0];
    const float* g    = (const float*)d_in[1];
    const float* be   = (const float*)d_in[2];
    const float* lshw = (const float*)d_in[3];
    const float* wts  = (const float*)d_in[4];
    const float* bias = (const float*)d_in[5];
    const float* hw   = (const float*)d_in[6];
    float* out = (float*)d_out;

    char* ws = (char*)d_ws;
    float* xn             = (float*)ws;          ws += 33554432;  // 8192x1024 f32
    unsigned short* xnb   = (unsigned short*)ws; ws += 16777216;  // 8192x1024 bf16
    unsigned short* lshb  = (unsigned short*)ws; ws += 8388608;   // 4096x1024 bf16
    unsigned short* wb    = (unsigned short*)ws; ws += 8388608;   // 4096x1024 bf16
    unsigned short* actb  = (unsigned short*)ws; ws += 16777216;  // 32x256x1024 bf16
    int* tcode            = (int*)ws;            ws += 131072;    // 8192x4
    int* ncode            = (int*)ws;            ws += 65536;     // 4096x4
    int* ids              = (int*)ws;            ws += 131072;    // 32x1024
    float* xbar           = (float*)ws;          ws += 131072;    // 32x1024
    float* wpsp           = (float*)ws;          ws += 2097152;   // 16x32x1024 f32
    float* wnsp           = (float*)ws;          ws += 2097152;   // 16x32x1024 f32
    float* closs          = (float*)ws;          ws += 128;       // 32

    ln_kernel<<<8192, 256, 0, stream>>>(hs, g, be, xn, xnb);
    cvt_kernel<<<8192, 256, 0, stream>>>(lshw, wts, lshb, wb);
    hash_kernel<<<3072, 256, 0, stream>>>(xn, lshw, hw, tcode, ncode);
    scoresel_kernel<<<32, 256, 0, stream>>>(tcode, ncode, ids);
    gemmA_kernel<<<dim3(8, 2, 32), 256, 0, stream>>>(xnb, lshb, ids, actb);
    gemmB_kernel<<<dim3(8, 2, 32), 256, 0, stream>>>(actb, wb, ids, bias, out);
    xbar_kernel<<<dim3(4, 32), 256, 0, stream>>>(xnb, xbar);
    gathersum_kernel<<<dim3(16, 32), 256, 0, stream>>>(ids, lshb, wpsp, wnsp);
    triplet_kernel<<<32, 256, 0, stream>>>(xbar, wpsp, wnsp, closs);
    final_loss_kernel<<<1, 64, 0, stream>>>(closs, out);
}